// Round 4
// baseline (192.220 us; speedup 1.0000x reference)
//
#include <hip/hip_runtime.h>

// SparseGrid gather: out[i, 18] = embeddings[t_idx[i], x_idx[i]+{-1,0,1}, y_idx[i]+{-1,0,1}, :2]
// embeddings: (600, 300, 300, 2) fp32, row-major. inputs: (N, 3) fp32 in [0,1).
//
// Round 4 (= round 3 with compile fix): reduce VMEM instruction count + L2 pollution.
//  - Row loads as span [yb, yb+2] (dwordx4 + dwordx2, 6 instrs instead of 9);
//    edge duplication (jnp.clip semantics) resolved with branchless selects.
//  - Output written as float4 non-temporal stores from LDS staging (coalesced,
//    half the store instructions, no L2 thrash from the 144 MB stream).
//  - Inputs read with non-temporal loads (read-once).
//  - Fix: nontemporal builtins need ext_vector types, not HIP float2 structs.

#define T_RES 600
#define X_RES 300
#define Y_RES 300
#define BLK 256

typedef float f4a8 __attribute__((ext_vector_type(4), aligned(8)));
typedef float f4   __attribute__((ext_vector_type(4)));
typedef float f2   __attribute__((ext_vector_type(2)));

__global__ __launch_bounds__(BLK) void sparsegrid_gather(
    const float* __restrict__ inputs,
    const float* __restrict__ emb,
    float* __restrict__ out,
    int n)
{
    __shared__ float lds[BLK * 19];

    int tid  = threadIdx.x;
    int base = blockIdx.x * BLK;
    int i    = base + tid;
    int npts = n - base;
    if (npts > BLK) npts = BLK;

    if (tid < npts) {
        float t = __builtin_nontemporal_load(inputs + 3 * i + 0);
        float x = __builtin_nontemporal_load(inputs + 3 * i + 1);
        float y = __builtin_nontemporal_load(inputs + 3 * i + 2);

        // Match numpy fp32 exactly: separate mul + add, round-to-nearest, NO fma.
        int ti = (int)__fadd_rn(__fmul_rn((float)(T_RES - 1), t), 0.5f);
        int xi = (int)__fadd_rn(__fmul_rn((float)(X_RES - 1), x), 0.5f);
        int yi = (int)__fadd_rn(__fmul_rn((float)(Y_RES - 1), y), 0.5f);
        ti = min(max(ti, 0), T_RES - 1);
        xi = min(max(xi, 0), X_RES - 1);
        yi = min(max(yi, 0), Y_RES - 1);

        // Consecutive in-bounds spans; duplicates at edges handled by selects.
        int xb = min(max(xi - 1, 0), X_RES - 3);   // rows xb, xb+1, xb+2
        int yb = min(max(yi - 1, 0), Y_RES - 3);   // cols yb, yb+1, yb+2
        bool x0 = (xi == 0), x2 = (xi == X_RES - 1);
        bool y0 = (yi == 0), y2 = (yi == Y_RES - 1);

        const f2* __restrict__ e2 = (const f2*)emb;
        int RA = (ti * X_RES + xb) * Y_RES + yb;   // f2 index of span start, row A
        int RB = RA + Y_RES;
        int RC = RB + Y_RES;

        // Load 3-row spans: dwordx4 (s0,s1) + dwordx2 (s2) each. 8-B aligned.
        f4a8 a01 = *(const f4a8*)(e2 + RA);  f2 a2 = e2[RA + 2];
        f4a8 b01 = *(const f4a8*)(e2 + RB);  f2 b2 = e2[RB + 2];
        f4a8 c01 = *(const f4a8*)(e2 + RC);  f2 c2 = e2[RC + 2];

        f2 aS0 = {a01.x, a01.y}, aS1 = {a01.z, a01.w};
        f2 bS0 = {b01.x, b01.y}, bS1 = {b01.z, b01.w};
        f2 cS0 = {c01.x, c01.y}, cS1 = {c01.z, c01.w};

        // y-select: span (s0,s1,s2) -> taps (v0,v1,v2) with clip duplication.
        // interior: (s0,s1,s2); yi==0: (s0,s0,s1); yi==299: (s1,s2,s2).
        f2 a0 = y2 ? aS1 : aS0, a1v = y0 ? aS0 : (y2 ? a2 : aS1), a2v = y0 ? aS1 : a2;
        f2 b0 = y2 ? bS1 : bS0, b1v = y0 ? bS0 : (y2 ? b2 : bS1), b2v = y0 ? bS1 : b2;
        f2 c0 = y2 ? cS1 : cS0, c1v = y0 ? cS0 : (y2 ? c2 : cS1), c2v = y0 ? cS1 : c2;

        // x-select: rows (A,B,C) -> output rows with clip duplication.
        // interior: (A,B,C); xi==0: (A,A,B); xi==299: (B,C,C).
        f2 r0_0 = x2 ? b0  : a0,  r0_1 = x2 ? b1v : a1v, r0_2 = x2 ? b2v : a2v;
        f2 r1_0 = x0 ? a0  : (x2 ? c0  : b0 );
        f2 r1_1 = x0 ? a1v : (x2 ? c1v : b1v);
        f2 r1_2 = x0 ? a2v : (x2 ? c2v : b2v);
        f2 r2_0 = x0 ? b0  : c0,  r2_1 = x0 ? b1v : c1v, r2_2 = x0 ? b2v : c2v;

        float* row = &lds[tid * 19];
        row[0]  = r0_0.x; row[1]  = r0_0.y;
        row[2]  = r0_1.x; row[3]  = r0_1.y;
        row[4]  = r0_2.x; row[5]  = r0_2.y;
        row[6]  = r1_0.x; row[7]  = r1_0.y;
        row[8]  = r1_1.x; row[9]  = r1_1.y;
        row[10] = r1_2.x; row[11] = r1_2.y;
        row[12] = r2_0.x; row[13] = r2_0.y;
        row[14] = r2_1.x; row[15] = r2_1.y;
        row[16] = r2_2.x; row[17] = r2_2.y;
    }

    __syncthreads();

    if (npts == BLK) {
        // Full block: 1152 float4s, coalesced non-temporal stores.
        f4* oblk4 = (f4*)(out + (size_t)base * 18);
        #pragma unroll
        for (int k = 0; k < 5; ++k) {
            int q = tid + BLK * k;
            if (q < (BLK * 18) / 4) {
                unsigned idx = 4u * q;
                f4 w;
                #pragma unroll
                for (int c = 0; c < 4; ++c) {
                    unsigned id = idx + c;
                    unsigned p = id / 18u;
                    unsigned e = id - 18u * p;
                    w[c] = lds[p * 19 + e];
                }
                __builtin_nontemporal_store(w, oblk4 + q);
            }
        }
    } else {
        // Tail block: f2 path (npts*18 not divisible by 4 in general).
        int total2 = npts * 9;
        f2* oblk = (f2*)(out + (size_t)base * 18);
        #pragma unroll
        for (int k = 0; k < 9; ++k) {
            int d2 = tid + BLK * k;
            if (d2 < total2) {
                int p = d2 / 9;
                int e = d2 - p * 9;
                f2 w;
                w.x = lds[p * 19 + 2 * e];
                w.y = lds[p * 19 + 2 * e + 1];
                __builtin_nontemporal_store(w, oblk + d2);
            }
        }
    }
}

extern "C" void kernel_launch(void* const* d_in, const int* in_sizes, int n_in,
                              void* d_out, int out_size, void* d_ws, size_t ws_size,
                              hipStream_t stream) {
    const float* inputs = (const float*)d_in[0];
    const float* emb    = (const float*)d_in[1];
    float* out          = (float*)d_out;

    int n = in_sizes[0] / 3;  // N_POINTS
    int grid = (n + BLK - 1) / BLK;
    sparsegrid_gather<<<grid, BLK, 0, stream>>>(inputs, emb, out, n);
}

// Round 5
// 156.098 us; speedup vs baseline: 1.2314x; 1.2314x over previous
//
#include <hip/hip_runtime.h>

// SparseGrid gather: out[i, 18] = embeddings[t_idx[i], x_idx[i]+{-1,0,1}, y_idx[i]+{-1,0,1}, :2]
// embeddings: (600, 300, 300, 2) fp32, row-major. inputs: (N, 3) fp32 in [0,1).
//
// Round 5: round-2 structure (direct 9-tap float2 gather, LDS-staged coalesced
// writes) + float4 full-block stores + nt input loads. The round-4 span-load/
// select rewrite regressed (VGPR pressure) and is reverted.

#define T_RES 600
#define X_RES 300
#define Y_RES 300
#define BLK 256

typedef float f4 __attribute__((ext_vector_type(4)));
typedef float f2 __attribute__((ext_vector_type(2)));

__global__ __launch_bounds__(BLK) void sparsegrid_gather(
    const float* __restrict__ inputs,
    const float* __restrict__ emb,
    float* __restrict__ out,
    int n)
{
    __shared__ float lds[BLK * 19];

    int tid  = threadIdx.x;
    int base = blockIdx.x * BLK;
    int i    = base + tid;
    int npts = n - base;
    if (npts > BLK) npts = BLK;

    if (tid < npts) {
        float t = __builtin_nontemporal_load(inputs + 3 * i + 0);
        float x = __builtin_nontemporal_load(inputs + 3 * i + 1);
        float y = __builtin_nontemporal_load(inputs + 3 * i + 2);

        // Match numpy fp32 exactly: separate mul + add, round-to-nearest, NO fma.
        int ti = (int)__fadd_rn(__fmul_rn((float)(T_RES - 1), t), 0.5f);
        int xi = (int)__fadd_rn(__fmul_rn((float)(X_RES - 1), x), 0.5f);
        int yi = (int)__fadd_rn(__fmul_rn((float)(Y_RES - 1), y), 0.5f);
        ti = min(max(ti, 0), T_RES - 1);
        xi = min(max(xi, 0), X_RES - 1);
        yi = min(max(yi, 0), Y_RES - 1);

        int xs0 = max(xi - 1, 0), xs2 = min(xi + 1, X_RES - 1);
        int ys0 = max(yi - 1, 0), ys1 = yi, ys2 = min(yi + 1, Y_RES - 1);

        const f2* __restrict__ e2 = (const f2*)emb;
        int tb = ti * X_RES;
        int r0 = (tb + xs0) * Y_RES;
        int r1 = (tb + xi ) * Y_RES;
        int r2 = (tb + xs2) * Y_RES;

        f2 v0 = e2[r0 + ys0];
        f2 v1 = e2[r0 + ys1];
        f2 v2 = e2[r0 + ys2];
        f2 v3 = e2[r1 + ys0];
        f2 v4 = e2[r1 + ys1];
        f2 v5 = e2[r1 + ys2];
        f2 v6 = e2[r2 + ys0];
        f2 v7 = e2[r2 + ys1];
        f2 v8 = e2[r2 + ys2];

        float* row = &lds[tid * 19];
        row[0]  = v0.x; row[1]  = v0.y;
        row[2]  = v1.x; row[3]  = v1.y;
        row[4]  = v2.x; row[5]  = v2.y;
        row[6]  = v3.x; row[7]  = v3.y;
        row[8]  = v4.x; row[9]  = v4.y;
        row[10] = v5.x; row[11] = v5.y;
        row[12] = v6.x; row[13] = v6.y;
        row[14] = v7.x; row[15] = v7.y;
        row[16] = v8.x; row[17] = v8.y;
    }

    __syncthreads();

    if (npts == BLK) {
        // Full block: 1152 coalesced float4 stores covering the 18 KiB slab.
        f4* oblk4 = (f4*)(out + (size_t)base * 18);
        #pragma unroll
        for (int k = 0; k < 5; ++k) {
            int q = tid + BLK * k;
            if (q < (BLK * 18) / 4) {
                unsigned idx = 4u * q;
                f4 w;
                #pragma unroll
                for (int c = 0; c < 4; ++c) {
                    unsigned id = idx + c;
                    unsigned p = id / 18u;
                    unsigned e = id - 18u * p;
                    w[c] = lds[p * 19 + e];
                }
                oblk4[q] = w;
            }
        }
    } else {
        // Tail block: float2 path (npts*18 not divisible by 4 in general).
        int total2 = npts * 9;
        f2* oblk = (f2*)(out + (size_t)base * 18);
        #pragma unroll
        for (int k = 0; k < 9; ++k) {
            int d2 = tid + BLK * k;
            if (d2 < total2) {
                int p = d2 / 9;
                int e = d2 - p * 9;
                f2 w;
                w.x = lds[p * 19 + 2 * e];
                w.y = lds[p * 19 + 2 * e + 1];
                oblk[d2] = w;
            }
        }
    }
}

extern "C" void kernel_launch(void* const* d_in, const int* in_sizes, int n_in,
                              void* d_out, int out_size, void* d_ws, size_t ws_size,
                              hipStream_t stream) {
    const float* inputs = (const float*)d_in[0];
    const float* emb    = (const float*)d_in[1];
    float* out          = (float*)d_out;

    int n = in_sizes[0] / 3;  // N_POINTS
    int grid = (n + BLK - 1) / BLK;
    sparsegrid_gather<<<grid, BLK, 0, stream>>>(inputs, emb, out, n);
}

// Round 6
// 153.949 us; speedup vs baseline: 1.2486x; 1.0140x over previous
//
#include <hip/hip_runtime.h>

// SparseGrid gather: out[i, 18] = embeddings[t_idx[i], x_idx[i]+{-1,0,1}, y_idx[i]+{-1,0,1}, :2]
// embeddings: (600, 300, 300, 2) fp32, row-major. inputs: (N, 3) fp32 in [0,1).
//
// Round 6: round-5 structure + NON-TEMPORAL output stores (single lever).
// The 144 MB output stream otherwise thrashes the 4 MB/XCD L2 that the
// scattered gather's repeat line-touches want to hit.

#define T_RES 600
#define X_RES 300
#define Y_RES 300
#define BLK 256

typedef float f4 __attribute__((ext_vector_type(4)));
typedef float f2 __attribute__((ext_vector_type(2)));

__global__ __launch_bounds__(BLK) void sparsegrid_gather(
    const float* __restrict__ inputs,
    const float* __restrict__ emb,
    float* __restrict__ out,
    int n)
{
    __shared__ float lds[BLK * 19];

    int tid  = threadIdx.x;
    int base = blockIdx.x * BLK;
    int i    = base + tid;
    int npts = n - base;
    if (npts > BLK) npts = BLK;

    if (tid < npts) {
        float t = __builtin_nontemporal_load(inputs + 3 * i + 0);
        float x = __builtin_nontemporal_load(inputs + 3 * i + 1);
        float y = __builtin_nontemporal_load(inputs + 3 * i + 2);

        // Match numpy fp32 exactly: separate mul + add, round-to-nearest, NO fma.
        int ti = (int)__fadd_rn(__fmul_rn((float)(T_RES - 1), t), 0.5f);
        int xi = (int)__fadd_rn(__fmul_rn((float)(X_RES - 1), x), 0.5f);
        int yi = (int)__fadd_rn(__fmul_rn((float)(Y_RES - 1), y), 0.5f);
        ti = min(max(ti, 0), T_RES - 1);
        xi = min(max(xi, 0), X_RES - 1);
        yi = min(max(yi, 0), Y_RES - 1);

        int xs0 = max(xi - 1, 0), xs2 = min(xi + 1, X_RES - 1);
        int ys0 = max(yi - 1, 0), ys1 = yi, ys2 = min(yi + 1, Y_RES - 1);

        const f2* __restrict__ e2 = (const f2*)emb;
        int tb = ti * X_RES;
        int r0 = (tb + xs0) * Y_RES;
        int r1 = (tb + xi ) * Y_RES;
        int r2 = (tb + xs2) * Y_RES;

        f2 v0 = e2[r0 + ys0];
        f2 v1 = e2[r0 + ys1];
        f2 v2 = e2[r0 + ys2];
        f2 v3 = e2[r1 + ys0];
        f2 v4 = e2[r1 + ys1];
        f2 v5 = e2[r1 + ys2];
        f2 v6 = e2[r2 + ys0];
        f2 v7 = e2[r2 + ys1];
        f2 v8 = e2[r2 + ys2];

        float* row = &lds[tid * 19];
        row[0]  = v0.x; row[1]  = v0.y;
        row[2]  = v1.x; row[3]  = v1.y;
        row[4]  = v2.x; row[5]  = v2.y;
        row[6]  = v3.x; row[7]  = v3.y;
        row[8]  = v4.x; row[9]  = v4.y;
        row[10] = v5.x; row[11] = v5.y;
        row[12] = v6.x; row[13] = v6.y;
        row[14] = v7.x; row[15] = v7.y;
        row[16] = v8.x; row[17] = v8.y;
    }

    __syncthreads();

    if (npts == BLK) {
        // Full block: 1152 coalesced non-temporal float4 stores (18 KiB slab).
        f4* oblk4 = (f4*)(out + (size_t)base * 18);
        #pragma unroll
        for (int k = 0; k < 5; ++k) {
            int q = tid + BLK * k;
            if (q < (BLK * 18) / 4) {
                unsigned idx = 4u * q;
                f4 w;
                #pragma unroll
                for (int c = 0; c < 4; ++c) {
                    unsigned id = idx + c;
                    unsigned p = id / 18u;
                    unsigned e = id - 18u * p;
                    w[c] = lds[p * 19 + e];
                }
                __builtin_nontemporal_store(w, oblk4 + q);
            }
        }
    } else {
        // Tail block: float2 path (npts*18 not divisible by 4 in general).
        int total2 = npts * 9;
        f2* oblk = (f2*)(out + (size_t)base * 18);
        #pragma unroll
        for (int k = 0; k < 9; ++k) {
            int d2 = tid + BLK * k;
            if (d2 < total2) {
                int p = d2 / 9;
                int e = d2 - p * 9;
                f2 w;
                w.x = lds[p * 19 + 2 * e];
                w.y = lds[p * 19 + 2 * e + 1];
                __builtin_nontemporal_store(w, oblk + d2);
            }
        }
    }
}

extern "C" void kernel_launch(void* const* d_in, const int* in_sizes, int n_in,
                              void* d_out, int out_size, void* d_ws, size_t ws_size,
                              hipStream_t stream) {
    const float* inputs = (const float*)d_in[0];
    const float* emb    = (const float*)d_in[1];
    float* out          = (float*)d_out;

    int n = in_sizes[0] / 3;  // N_POINTS
    int grid = (n + BLK - 1) / BLK;
    sparsegrid_gather<<<grid, BLK, 0, stream>>>(inputs, emb, out, n);
}